// Round 2
// baseline (325.695 us; speedup 1.0000x reference)
//
#include <hip/hip_runtime.h>
#include <cfloat>

#define NROWS  32768
#define NCODES 8192
#define DDIM   256
#define CT     64                // codes per stage/tile (32 KB), 3-buffer ring
#define TPB    (NCODES / CT)     // 128 stages; KG=1: every block scans all codes
#define RPB    128               // rows per block; grid = 256 blocks (1/CU)

typedef __attribute__((ext_vector_type(8))) __bf16 bf16x8;
typedef __attribute__((ext_vector_type(4))) float  f32x4;

// ---- kernel A: codebook fp32 -> bf16 + fused esq ----
__global__ __launch_bounds__(256)
void cvt_cb(const float* __restrict__ cb, __bf16* __restrict__ cbb,
            float* __restrict__ esq) {
    const size_t i = (size_t)(blockIdx.x * 256 + threadIdx.x) * 8;
    const float4 f0 = *(const float4*)(cb + i);
    const float4 f1 = *(const float4*)(cb + i + 4);
    bf16x8 v;
    v[0] = (__bf16)f0.x; v[1] = (__bf16)f0.y; v[2] = (__bf16)f0.z; v[3] = (__bf16)f0.w;
    v[4] = (__bf16)f1.x; v[5] = (__bf16)f1.y; v[6] = (__bf16)f1.z; v[7] = (__bf16)f1.w;
    *(bf16x8*)(cbb + i) = v;
    float s = f0.x * f0.x + f0.y * f0.y + f0.z * f0.z + f0.w * f0.w
            + f1.x * f1.x + f1.y * f1.y + f1.z * f1.z + f1.w * f1.w;
    for (int o = 16; o > 0; o >>= 1) s += __shfl_down(s, o, 32);
    if ((threadIdx.x & 31) == 0) esq[i >> 8] = s;
}

// ---- kernel B: occupancy-first MFMA scan ----
// Post-mortem R1: one 16x16x32 MFMA = ~16 SIMD-cycles (2075 TF ubench is
// per-CU); at 2 waves/SIMD the measured MfmaUtil 26% == pipe demand /
// stage time exactly -> latency-bound at occupancy 2. This version: 1024
// thr / 16 waves (4 row-groups x 4 col-groups), 32 rows/wave so Af = 64
// VGPR and total stays <=128 -> 4 waves/SIMD. KG=1, 128 rows/block: B-tile
// still read by only 4 row-groups (LDS 128KB/stage ~ MFMA 1030 cyc/stage),
// every block reads the SAME tile per stage (L2-friendly), z read once.
// 3-slot ring, prefetch distance 2, counted vmcnt(2) (2 loads in flight),
// argmin after barrier so it overlaps other waves' next stage.
__global__ __launch_bounds__(1024, 4)
void vq_mfma(const float* __restrict__ z, const __bf16* __restrict__ cbb,
             const float* __restrict__ esq, int* __restrict__ pI) {
    __shared__ __align__(16) __bf16 Bb[3][CT * DDIM];   // 3 x 32 KB ring
    __shared__ __align__(16) float  esqLds[NCODES];     // 32 KB
    __shared__ float RedV[RPB][4];
    __shared__ int   RedI[RPB][4];

    const int rowbase = blockIdx.x * RPB;
    const int tid = threadIdx.x;
    const int w = tid >> 6, l = tid & 63;
    const int rh = w >> 2, ch = w & 3;     // 4 row-groups x 4 col-groups
    const int lm = l & 15, lq = l >> 4;
    const int loff = lm * DDIM + lq * 8;   // lane offset within a 16-code group
    // staging role: wave w stages pieces (j, g): g = w&3, j = (w>>2)*2 + jj
    const int g = w & 3, jb = (w >> 2) * 2;

    // ---- prologue: issue stages 0 and 1 into ring slots 0/1 ----
#pragma unroll
    for (int s0 = 0; s0 < 2; ++s0) {
        const __bf16* src = cbb + (size_t)(s0 * CT + g * 16) * DDIM;
#pragma unroll
        for (int jj = 0; jj < 2; ++jj) {
            const int j = jb + jj;
            __builtin_amdgcn_global_load_lds(
                (const __attribute__((address_space(1))) void*)(src + j * 32 + loff),
                (__attribute__((address_space(3))) void*)(&Bb[s0][(j * 4 + g) * 512]),
                16, 0, 0);
        }
    }

    // ---- esq -> LDS once (8192 floats; 8 per thread) ----
    {
        const float4 q0 = *(const float4*)(esq + tid * 8);
        const float4 q1 = *(const float4*)(esq + tid * 8 + 4);
        *(float4*)&esqLds[tid * 8]     = q0;
        *(float4*)&esqLds[tid * 8 + 4] = q1;
    }

    // ---- A prologue: 32 rows x 256 k per wave -> 16 bf16x8 frags (-2*z) ----
    bf16x8 Af[2][8];   // [row-seg fr][k-chunk] = 64 VGPRs
    {
        const float* zp = z + (size_t)(rowbase + rh * 32 + lm) * DDIM + lq * 8;
#pragma unroll
        for (int s = 0; s < 2; ++s)
#pragma unroll
            for (int kc = 0; kc < 8; ++kc) {
                const float4 f0 = *(const float4*)(zp + s * 16 * DDIM + kc * 32);
                const float4 f1 = *(const float4*)(zp + s * 16 * DDIM + kc * 32 + 4);
                bf16x8 v;
                v[0] = (__bf16)(-2.f * f0.x); v[1] = (__bf16)(-2.f * f0.y);
                v[2] = (__bf16)(-2.f * f0.z); v[3] = (__bf16)(-2.f * f0.w);
                v[4] = (__bf16)(-2.f * f1.x); v[5] = (__bf16)(-2.f * f1.y);
                v[6] = (__bf16)(-2.f * f1.z); v[7] = (__bf16)(-2.f * f1.w);
                Af[s][kc] = v;
            }
    }

    float bestV[8];
    int   bestI[8];
#pragma unroll
    for (int s = 0; s < 8; ++s) { bestV[s] = FLT_MAX; bestI[s] = 0; }

    // one full drain at the prologue only
    asm volatile("s_waitcnt vmcnt(0) lgkmcnt(0)" ::: "memory");
    __builtin_amdgcn_s_barrier();

    unsigned bc = 0, bn = 1, bp = 2;   // ring: current / next / prefetch-dest
#pragma unroll 1
    for (int t = 0; t < TPB; ++t) {
        // issue stage t+2 into slot bp (readers retired at barrier t-1)
        if (t + 2 < TPB) {
            const __bf16* src = cbb + (size_t)((t + 2) * CT + g * 16) * DDIM;
#pragma unroll
            for (int jj = 0; jj < 2; ++jj) {
                const int j = jb + jj;
                __builtin_amdgcn_global_load_lds(
                    (const __attribute__((address_space(1))) void*)(src + j * 32 + loff),
                    (__attribute__((address_space(3))) void*)(&Bb[bp][(j * 4 + g) * 512]),
                    16, 0, 0);
            }
        }

        // acc init = esq broadcast (LDS; lgkm-tracked, vmcnt stays clean)
        const float e = esqLds[t * CT + ch * 16 + lm];
        f32x4 acc[2];
        acc[0] = (f32x4){e, e, e, e};
        acc[1] = (f32x4){e, e, e, e};

        const __bf16* Bc = &Bb[bc][0];
        __builtin_amdgcn_s_setprio(1);
#pragma unroll
        for (int c = 0; c < 8; ++c) {
            const bf16x8 bfv = *(const bf16x8*)(Bc + (c * 4 + ch) * 512 + l * 8);
            acc[0] = __builtin_amdgcn_mfma_f32_16x16x32_bf16(Af[0][c], bfv, acc[0], 0, 0, 0);
            acc[1] = __builtin_amdgcn_mfma_f32_16x16x32_bf16(Af[1][c], bfv, acc[1], 0, 0, 0);
        }
        __builtin_amdgcn_s_setprio(0);

        // counted wait: t+1's 2 loads must be done; t+2's 2 stay in flight
        // ACROSS the barrier. lgkmcnt(0) closes the WAR window on Bb[bc].
        if (t + 1 < TPB) {
            if (t + 2 < TPB)
                asm volatile("s_waitcnt vmcnt(2) lgkmcnt(0)" ::: "memory");
            else
                asm volatile("s_waitcnt vmcnt(0) lgkmcnt(0)" ::: "memory");
            __builtin_amdgcn_s_barrier();
        }

        // fused argmin on registers (overlaps other waves' next stage).
        // tiles ascend; strict < keeps smallest index
        const int colI = t * CT + ch * 16 + lm;
#pragma unroll
        for (int fr = 0; fr < 2; ++fr)
#pragma unroll
            for (int i = 0; i < 4; ++i) {
                const float sc = acc[fr][i];
                const int slot = fr * 4 + i;
                if (sc < bestV[slot]) { bestV[slot] = sc; bestI[slot] = colI; }
            }

        const unsigned tmp = bc; bc = bn; bn = bp; bp = tmp;
    }

    // cross-lane argmin over the 16 col-lanes (lane bits 0..3 = lm)
#pragma unroll
    for (int s = 0; s < 8; ++s) {
#pragma unroll
        for (int m = 1; m < 16; m <<= 1) {
            const float v2 = __shfl_xor(bestV[s], m);
            const int   i2 = __shfl_xor(bestI[s], m);
            if (v2 < bestV[s] || (v2 == bestV[s] && i2 < bestI[s])) {
                bestV[s] = v2; bestI[s] = i2;
            }
        }
    }
    if (lm == 0) {
#pragma unroll
        for (int s = 0; s < 8; ++s) {   // row = rh*32 + (s>>2)*16 + lq*4 + (s&3)
            const int rl = rh * 32 + (s >> 2) * 16 + lq * 4 + (s & 3);
            RedV[rl][ch] = bestV[s]; RedI[rl][ch] = bestI[s];
        }
    }
    __syncthreads();
    if (tid < RPB) {  // combine the four col-quarters; tie -> smaller index
        float v = RedV[tid][0]; int bi = RedI[tid][0];
#pragma unroll
        for (int q = 1; q < 4; ++q) {
            const float v2 = RedV[tid][q]; const int i2 = RedI[tid][q];
            if (v2 < v || (v2 == v && i2 < bi)) { v = v2; bi = i2; }
        }
        pI[rowbase + tid] = bi;
    }
}

// ---- kernel C: gather (fp32), STE out, loss partials ----
__global__ __launch_bounds__(256)
void vq_finalize(const float* __restrict__ z, const float* __restrict__ cb,
                 const int* __restrict__ pI,
                 float* __restrict__ out, float* __restrict__ bsum) {
    __shared__ float sSum[4];
    const int tid = threadIdx.x;
    const int rw = tid >> 6, lane = tid & 63;
    const int row = blockIdx.x * 4 + rw;

    const int idx = pI[row];   // wave-uniform load

    const float4 zv = *(const float4*)(z  + (size_t)row * DDIM + lane * 4);
    const float4 ev = *(const float4*)(cb + (size_t)idx * DDIM + lane * 4);
    float4 d, o;
    d.x = ev.x - zv.x; d.y = ev.y - zv.y; d.z = ev.z - zv.z; d.w = ev.w - zv.w;
    o.x = zv.x + d.x;  o.y = zv.y + d.y;  o.z = zv.z + d.z;  o.w = zv.w + d.w;
    *(float4*)(out + (size_t)row * DDIM + lane * 4) = o;

    float s = d.x * d.x + d.y * d.y + d.z * d.z + d.w * d.w;
    for (int off = 32; off > 0; off >>= 1) s += __shfl_down(s, off);
    if (lane == 0) sSum[rw] = s;
    __syncthreads();
    if (tid == 0) bsum[blockIdx.x] = sSum[0] + sSum[1] + sSum[2] + sSum[3];
}

// ---- kernel D: loss ----
__global__ __launch_bounds__(256)
void loss_final(const float* __restrict__ bsum, float* __restrict__ out) {
    __shared__ float red[4];
    const int tid = threadIdx.x;
    float s = 0.f;
    for (int i = tid; i < NROWS / 4; i += 256) s += bsum[i];
    for (int off = 32; off > 0; off >>= 1) s += __shfl_down(s, off);
    const int wv = tid >> 6, lane = tid & 63;
    if (lane == 0) red[wv] = s;
    __syncthreads();
    if (tid == 0) {
        const float tot = red[0] + red[1] + red[2] + red[3];
        out[(size_t)NROWS * DDIM] = tot * (1.25f / (float)((size_t)NROWS * DDIM));
    }
}

extern "C" void kernel_launch(void* const* d_in, const int* in_sizes, int n_in,
                              void* d_out, int out_size, void* d_ws, size_t ws_size,
                              hipStream_t stream) {
    const float* z  = (const float*)d_in[0];
    const float* cb = (const float*)d_in[1];
    float* out = (float*)d_out;

    // bf16 codebook staged at head of d_out (4 MB; consumed by vq_mfma
    // before vq_finalize overwrites the region)
    __bf16* cbf = (__bf16*)d_out;

    // workspace carve
    float* esq  = (float*)d_ws;                 // 8192 floats
    int*   pI   = (int*)(esq + NCODES);         // 32768 ints
    float* bsum = (float*)(pI + NROWS);         // 8192 floats

    cvt_cb<<<NCODES * DDIM / 8 / 256, 256, 0, stream>>>(cb, cbf, esq);
    vq_mfma<<<NROWS / RPB, 1024, 0, stream>>>(z, cbf, esq, pI);
    vq_finalize<<<NROWS / 4, 256, 0, stream>>>(z, cb, pI, out, bsum);
    loss_final<<<1, 256, 0, stream>>>(bsum, out);
}

// Round 3
// 251.347 us; speedup vs baseline: 1.2958x; 1.2958x over previous
//
#include <hip/hip_runtime.h>
#include <cfloat>

#define NROWS  32768
#define NCODES 8192
#define DDIM   256
#define KG     2                 // code-split; grid = 256 row-tiles * 2 = 512 blocks
#define CPB    (NCODES / KG)     // 4096 codes per block
#define CT     64                // codes per stage (32 KB tile), double-buffered
#define TPB    (CPB / CT)        // 64 stages per block
#define RPB    128               // rows per block

typedef __attribute__((ext_vector_type(8))) __bf16 bf16x8;
typedef __attribute__((ext_vector_type(4))) float  f32x4;

// ---- kernel A: codebook fp32 -> bf16 + fused esq ----
__global__ __launch_bounds__(256)
void cvt_cb(const float* __restrict__ cb, __bf16* __restrict__ cbb,
            float* __restrict__ esq) {
    const size_t i = (size_t)(blockIdx.x * 256 + threadIdx.x) * 8;
    const float4 f0 = *(const float4*)(cb + i);
    const float4 f1 = *(const float4*)(cb + i + 4);
    bf16x8 v;
    v[0] = (__bf16)f0.x; v[1] = (__bf16)f0.y; v[2] = (__bf16)f0.z; v[3] = (__bf16)f0.w;
    v[4] = (__bf16)f1.x; v[5] = (__bf16)f1.y; v[6] = (__bf16)f1.z; v[7] = (__bf16)f1.w;
    *(bf16x8*)(cbb + i) = v;
    float s = f0.x * f0.x + f0.y * f0.y + f0.z * f0.z + f0.w * f0.w
            + f1.x * f1.x + f1.y * f1.y + f1.z * f1.z + f1.w * f1.w;
    for (int o = 16; o > 0; o >>= 1) s += __shfl_down(s, o, 32);
    if ((threadIdx.x & 31) == 0) esq[i >> 8] = s;
}

// ---- kernel B: 2-blocks/CU barrier-overlap MFMA scan ----
// Post-mortem R0-R2: MfmaUtil pinned at 24-28% across three sync structures;
// the shared trait was 1 block/CU (LDS >=116 KB) -> every per-stage barrier
// idles the WHOLE CU during rendezvous+drain (~3x stall multiplier). m97
// datapoint: same 2-barrier loop at ~3 blocks/CU reaches 37% MfmaUtil --
// cross-BLOCK overlap hides the drain, not waves-in-block. This version:
// LDS 66 KB (CT=64 dbuf, esq in regs) -> 2 co-resident blocks/CU, two
// independent barrier domains. 512 thr / 8 waves (4 row-groups x 2
// col-groups), 32 rows/wave (Af=64 VGPR, total ~125 <= 128 at 4 w/EU).
// Plain __syncthreads (drain covered by sibling block); no setprio.
__global__ __launch_bounds__(512, 4)
void vq_mfma(const float* __restrict__ z, const __bf16* __restrict__ cbb,
             const float* __restrict__ esq,
             float* __restrict__ pV, int* __restrict__ pI) {
    __shared__ __align__(16) __bf16 Bb[2][CT * DDIM];   // 2 x 32 KB
    __shared__ float RedV[RPB][2];
    __shared__ int   RedI[RPB][2];

    const int rowbase  = (blockIdx.x >> 1) * RPB;
    const int kg       = blockIdx.x & 1;
    const int codebase = kg * CPB;

    const int tid = threadIdx.x;
    const int w = tid >> 6, l = tid & 63;
    const int rh = w >> 1, ch = w & 1;     // 4 row-groups x 2 col-groups
    const int lm = l & 15, lq = l >> 4;
    const int loff = lm * DDIM + lq * 8;   // lane offset within a 16-code group
    // staging role: wave w stages group g (16 codes) x k-chunks jb..jb+3
    const int g = w & 3, jb = (w >> 2) * 4;

    // ---- stage 0 loads first (overlap with A conversion below) ----
#pragma unroll
    for (int jj = 0; jj < 4; ++jj) {
        const int j = jb + jj;
        __builtin_amdgcn_global_load_lds(
            (const __attribute__((address_space(1))) void*)
                (cbb + (size_t)(codebase + g * 16) * DDIM + j * 32 + loff),
            (__attribute__((address_space(3))) void*)(&Bb[0][(j * 4 + g) * 512]),
            16, 0, 0);
    }

    // ---- A prologue: 32 rows x 256 k per wave -> 16 bf16x8 frags (-2*z) ----
    bf16x8 Af[2][8];   // [row-frag][k-chunk] = 64 VGPRs
    {
        const float* zp = z + (size_t)(rowbase + rh * 32 + lm) * DDIM + lq * 8;
#pragma unroll
        for (int s = 0; s < 2; ++s)
#pragma unroll
            for (int kc = 0; kc < 8; ++kc) {
                const float4 f0 = *(const float4*)(zp + s * 16 * DDIM + kc * 32);
                const float4 f1 = *(const float4*)(zp + s * 16 * DDIM + kc * 32 + 4);
                bf16x8 v;
                v[0] = (__bf16)(-2.f * f0.x); v[1] = (__bf16)(-2.f * f0.y);
                v[2] = (__bf16)(-2.f * f0.z); v[3] = (__bf16)(-2.f * f0.w);
                v[4] = (__bf16)(-2.f * f1.x); v[5] = (__bf16)(-2.f * f1.y);
                v[6] = (__bf16)(-2.f * f1.z); v[7] = (__bf16)(-2.f * f1.w);
                Af[s][kc] = v;
            }
    }

    // esq for stage 0 (ping-ponged across stages; 2 regs live)
    float evc[2], evn[2];
#pragma unroll
    for (int fc = 0; fc < 2; ++fc)
        evc[fc] = esq[codebase + (ch * 2 + fc) * 16 + lm];

    float bestV[8];
    int   bestI[8];
#pragma unroll
    for (int s = 0; s < 8; ++s) { bestV[s] = FLT_MAX; bestI[s] = 0; }

    __syncthreads();   // stage 0 staged

    int buf = 0;
#pragma unroll 1
    for (int t = 0; t < TPB; ++t) {
        // issue next stage's 32 KB into the other buffer FIRST (its readers
        // finished before the previous barrier, so overwrite is safe)
        if (t + 1 < TPB) {
            const __bf16* base = cbb + (size_t)(codebase + (t + 1) * CT + g * 16) * DDIM;
#pragma unroll
            for (int jj = 0; jj < 4; ++jj) {
                const int j = jb + jj;
                __builtin_amdgcn_global_load_lds(
                    (const __attribute__((address_space(1))) void*)(base + j * 32 + loff),
                    (__attribute__((address_space(3))) void*)(&Bb[buf ^ 1][(j * 4 + g) * 512]),
                    16, 0, 0);
            }
        }
        {   // prefetch next stage's esq (registers; 2 loads)
            const int tn = (t + 1) & (TPB - 1);
#pragma unroll
            for (int fc = 0; fc < 2; ++fc)
                evn[fc] = esq[codebase + tn * CT + (ch * 2 + fc) * 16 + lm];
        }

        f32x4 acc[2][2];
#pragma unroll
        for (int fr = 0; fr < 2; ++fr)
#pragma unroll
            for (int fc = 0; fc < 2; ++fc) {
                const float e = evc[fc];
                acc[fr][fc] = (f32x4){e, e, e, e};
            }

        const __bf16* Bc = &Bb[buf][0];
#pragma unroll
        for (int c = 0; c < 8; ++c) {
            bf16x8 bfv[2];
#pragma unroll
            for (int fc = 0; fc < 2; ++fc)
                bfv[fc] = *(const bf16x8*)(Bc + (c * 4 + ch * 2 + fc) * 512 + l * 8);
#pragma unroll
            for (int fr = 0; fr < 2; ++fr)
#pragma unroll
                for (int fc = 0; fc < 2; ++fc)
                    acc[fr][fc] = __builtin_amdgcn_mfma_f32_16x16x32_bf16(
                        Af[fr][c], bfv[fc], acc[fr][fc], 0, 0, 0);
        }

        // fused argmin (tiles ascend; fc ascend = cols ascend; strict <)
#pragma unroll
        for (int fr = 0; fr < 2; ++fr)
#pragma unroll
            for (int fc = 0; fc < 2; ++fc) {
                const int colI = codebase + t * CT + (ch * 2 + fc) * 16 + lm;
#pragma unroll
                for (int i = 0; i < 4; ++i) {
                    const float sc = acc[fr][fc][i];
                    const int slot = fr * 4 + i;
                    if (sc < bestV[slot]) { bestV[slot] = sc; bestI[slot] = colI; }
                }
            }
#pragma unroll
        for (int fc = 0; fc < 2; ++fc) evc[fc] = evn[fc];

        __syncthreads();   // drain covered by the sibling block on this CU
        buf ^= 1;
    }

    // cross-lane argmin over the 16 col-lanes (lane bits 0..3 = lm)
#pragma unroll
    for (int s = 0; s < 8; ++s) {
#pragma unroll
        for (int m = 1; m < 16; m <<= 1) {
            const float v2 = __shfl_xor(bestV[s], m);
            const int   i2 = __shfl_xor(bestI[s], m);
            if (v2 < bestV[s] || (v2 == bestV[s] && i2 < bestI[s])) {
                bestV[s] = v2; bestI[s] = i2;
            }
        }
    }
    if (lm == 0) {
#pragma unroll
        for (int s = 0; s < 8; ++s) {   // row = rh*32 + fr*16 + lq*4 + i
            const int rl = rh * 32 + (s >> 2) * 16 + lq * 4 + (s & 3);
            RedV[rl][ch] = bestV[s]; RedI[rl][ch] = bestI[s];
        }
    }
    __syncthreads();
    if (tid < RPB) {  // combine the two col-halves; tie -> smaller index
        float v = RedV[tid][0]; int bi = RedI[tid][0];
        const float v2 = RedV[tid][1]; const int i2 = RedI[tid][1];
        if (v2 < v || (v2 == v && i2 < bi)) { v = v2; bi = i2; }
        const int row = rowbase + tid;
        pV[row * KG + kg] = v; pI[row * KG + kg] = bi;
    }
}

// ---- kernel C: combine K-groups, gather (fp32), STE out, loss partials ----
__global__ __launch_bounds__(256)
void vq_finalize(const float* __restrict__ z, const float* __restrict__ cb,
                 const float* __restrict__ pV, const int* __restrict__ pI,
                 float* __restrict__ out, float* __restrict__ bsum) {
    __shared__ float sSum[4];
    __shared__ int   sIdx[4];
    const int tid = threadIdx.x;
    const int rw = tid >> 6, lane = tid & 63;
    const int row = blockIdx.x * 4 + rw;

    if (lane == 0) {  // ascending kg = ascending index; strict < keeps first
        float v = pV[row * KG]; int bi = pI[row * KG];
        const float v2 = pV[row * KG + 1]; const int i2 = pI[row * KG + 1];
        if (v2 < v || (v2 == v && i2 < bi)) { v = v2; bi = i2; }
        sIdx[rw] = bi;
    }
    __syncthreads();
    const int idx = sIdx[rw];

    const float4 zv = *(const float4*)(z  + (size_t)row * DDIM + lane * 4);
    const float4 ev = *(const float4*)(cb + (size_t)idx * DDIM + lane * 4);
    float4 d, o;
    d.x = ev.x - zv.x; d.y = ev.y - zv.y; d.z = ev.z - zv.z; d.w = ev.w - zv.w;
    o.x = zv.x + d.x;  o.y = zv.y + d.y;  o.z = zv.z + d.z;  o.w = zv.w + d.w;
    *(float4*)(out + (size_t)row * DDIM + lane * 4) = o;

    float s = d.x * d.x + d.y * d.y + d.z * d.z + d.w * d.w;
    for (int off = 32; off > 0; off >>= 1) s += __shfl_down(s, off);
    if (lane == 0) sSum[rw] = s;
    __syncthreads();
    if (tid == 0) bsum[blockIdx.x] = sSum[0] + sSum[1] + sSum[2] + sSum[3];
}

// ---- kernel D: loss ----
__global__ __launch_bounds__(256)
void loss_final(const float* __restrict__ bsum, float* __restrict__ out) {
    __shared__ float red[4];
    const int tid = threadIdx.x;
    float s = 0.f;
    for (int i = tid; i < NROWS / 4; i += 256) s += bsum[i];
    for (int off = 32; off > 0; off >>= 1) s += __shfl_down(s, off);
    const int wv = tid >> 6, lane = tid & 63;
    if (lane == 0) red[wv] = s;
    __syncthreads();
    if (tid == 0) {
        const float tot = red[0] + red[1] + red[2] + red[3];
        out[(size_t)NROWS * DDIM] = tot * (1.25f / (float)((size_t)NROWS * DDIM));
    }
}

extern "C" void kernel_launch(void* const* d_in, const int* in_sizes, int n_in,
                              void* d_out, int out_size, void* d_ws, size_t ws_size,
                              hipStream_t stream) {
    const float* z  = (const float*)d_in[0];
    const float* cb = (const float*)d_in[1];
    float* out = (float*)d_out;

    // bf16 codebook staged at head of d_out (4 MB; consumed by vq_mfma
    // before vq_finalize overwrites the region)
    __bf16* cbf = (__bf16*)d_out;

    // workspace carve (~580 KB)
    float* esq  = (float*)d_ws;                 // 8192
    float* pV   = esq + NCODES;                 // 32768*2
    int*   pI   = (int*)(pV + NROWS * KG);      // 32768*2
    float* bsum = (float*)(pI + NROWS * KG);    // 8192

    cvt_cb<<<NCODES * DDIM / 8 / 256, 256, 0, stream>>>(cb, cbf, esq);
    vq_mfma<<<(NROWS / RPB) * KG, 512, 0, stream>>>(z, cbf, esq, pV, pI);
    vq_finalize<<<NROWS / 4, 256, 0, stream>>>(z, cb, pV, pI, out, bsum);
    loss_final<<<1, 256, 0, stream>>>(bsum, out);
}

// Round 4
// 246.768 us; speedup vs baseline: 1.3198x; 1.0186x over previous
//
#include <hip/hip_runtime.h>
#include <cfloat>

#define NROWS  32768
#define NCODES 8192
#define DDIM   256
#define KG     4                 // code-split; grid = 128 row-tiles * 4 = 512 blocks
#define CPB    (NCODES / KG)     // 2048 codes per block
#define CT     64                // codes per stage (32 KB tile), double-buffered
#define TPB    (CPB / CT)        // 32 stages per block
#define RPB    256               // rows per block (4 waves x 64 rows)

typedef __attribute__((ext_vector_type(8))) __bf16 bf16x8;
typedef __attribute__((ext_vector_type(4))) float  f32x4;

// ---- kernel A: codebook fp32 -> bf16 + fused esq ----
__global__ __launch_bounds__(256)
void cvt_cb(const float* __restrict__ cb, __bf16* __restrict__ cbb,
            float* __restrict__ esq) {
    const size_t i = (size_t)(blockIdx.x * 256 + threadIdx.x) * 8;
    const float4 f0 = *(const float4*)(cb + i);
    const float4 f1 = *(const float4*)(cb + i + 4);
    bf16x8 v;
    v[0] = (__bf16)f0.x; v[1] = (__bf16)f0.y; v[2] = (__bf16)f0.z; v[3] = (__bf16)f0.w;
    v[4] = (__bf16)f1.x; v[5] = (__bf16)f1.y; v[6] = (__bf16)f1.z; v[7] = (__bf16)f1.w;
    *(bf16x8*)(cbb + i) = v;
    float s = f0.x * f0.x + f0.y * f0.y + f0.z * f0.z + f0.w * f0.w
            + f1.x * f1.x + f1.y * f1.y + f1.z * f1.z + f1.w * f1.w;
    for (int o = 16; o > 0; o >>= 1) s += __shfl_down(s, o, 32);
    if ((threadIdx.x & 31) == 0) esq[i >> 8] = s;
}

// ---- kernel B: 64-rows/wave reuse-4 MFMA scan, 2 blocks/CU ----
// Post-mortem R3: 2 barrier domains/CU worked (26->35% MfmaUtil) but LDS
// reads were the top demand (16.4 MB/CU = 193k cyc at 85 B/cyc vs MFMA
// 131k). LDS-bytes/MFMA scales as 1/(rows-per-wave/16): going 32->64
// rows/wave halves LDS traffic (96k cyc) and halves per-MFMA VALU/stage
// overhead, leaving MFMA (131k cyc = 55 us floor) dominant. Geometry:
// 256-thr blocks, 4 waves x 64 rows = 256 rows/block; each wave consumes
// the whole 64-code tile (rows partition across waves -> NO cross-wave
// argmin reduction). KG=4 -> 512 blocks = exactly 2/CU (two barrier
// domains). VGPR ~216 (Af=128) -> 2 waves/SIMD; each wave has 2048 cyc
// MFMA with 8 indep chains between barriers, sibling block hides drains.
// fc processed in two halves/stage to keep acc at 32 VGPRs.
__global__ __launch_bounds__(256, 2)
void vq_mfma(const float* __restrict__ z, const __bf16* __restrict__ cbb,
             const float* __restrict__ esq,
             float* __restrict__ pV, int* __restrict__ pI) {
    __shared__ __align__(16) __bf16 Bb[2][CT * DDIM];   // 2 x 32 KB

    const int rowbase  = (blockIdx.x >> 2) * RPB;
    const int kg       = blockIdx.x & 3;
    const int codebase = kg * CPB;

    const int tid = threadIdx.x;
    const int w = tid >> 6, l = tid & 63;       // wave = row-group (64 rows)
    const int lm = l & 15, lq = l >> 4;
    const int loff = lm * DDIM + lq * 8;        // lane offset in a 16-code group

    // ---- stage 0 loads first (overlap with A conversion below) ----
    // wave w stages code-group w (16 codes) x 8 k-chunks; piece = j*4 + w
#pragma unroll
    for (int j = 0; j < 8; ++j) {
        __builtin_amdgcn_global_load_lds(
            (const __attribute__((address_space(1))) void*)
                (cbb + (size_t)(codebase + w * 16) * DDIM + j * 32 + loff),
            (__attribute__((address_space(3))) void*)(&Bb[0][(j * 4 + w) * 512]),
            16, 0, 0);
    }

    // ---- A prologue: 64 rows x 256 k per wave -> 32 bf16x8 frags (-2*z) ----
    bf16x8 Af[4][8];   // [row-seg][k-chunk] = 128 VGPRs
    {
        const float* zp = z + (size_t)(rowbase + w * 64 + lm) * DDIM + lq * 8;
#pragma unroll
        for (int s = 0; s < 4; ++s)
#pragma unroll
            for (int kc = 0; kc < 8; ++kc) {
                const float4 f0 = *(const float4*)(zp + s * 16 * DDIM + kc * 32);
                const float4 f1 = *(const float4*)(zp + s * 16 * DDIM + kc * 32 + 4);
                bf16x8 v;
                v[0] = (__bf16)(-2.f * f0.x); v[1] = (__bf16)(-2.f * f0.y);
                v[2] = (__bf16)(-2.f * f0.z); v[3] = (__bf16)(-2.f * f0.w);
                v[4] = (__bf16)(-2.f * f1.x); v[5] = (__bf16)(-2.f * f1.y);
                v[6] = (__bf16)(-2.f * f1.z); v[7] = (__bf16)(-2.f * f1.w);
                Af[s][kc] = v;
            }
    }

    // esq for stage 0 (ping-ponged; 4 regs per buffer)
    float evc[4], evn[4];
#pragma unroll
    for (int fc = 0; fc < 4; ++fc)
        evc[fc] = esq[codebase + fc * 16 + lm];

    float bestV[16];
    int   bestI[16];
#pragma unroll
    for (int s = 0; s < 16; ++s) { bestV[s] = FLT_MAX; bestI[s] = 0; }

    __syncthreads();   // stage 0 staged

    int buf = 0;
#pragma unroll 1
    for (int t = 0; t < TPB; ++t) {
        // issue next stage's 32 KB into the other buffer FIRST
        if (t + 1 < TPB) {
            const __bf16* base = cbb + (size_t)(codebase + (t + 1) * CT + w * 16) * DDIM;
#pragma unroll
            for (int j = 0; j < 8; ++j) {
                __builtin_amdgcn_global_load_lds(
                    (const __attribute__((address_space(1))) void*)(base + j * 32 + loff),
                    (__attribute__((address_space(3))) void*)(&Bb[buf ^ 1][(j * 4 + w) * 512]),
                    16, 0, 0);
            }
        }
        {   // prefetch next stage's esq (registers; 4 loads)
            const int tn = (t + 1) & (TPB - 1);
#pragma unroll
            for (int fc = 0; fc < 4; ++fc)
                evn[fc] = esq[codebase + tn * CT + fc * 16 + lm];
        }

        const __bf16* Bc = &Bb[buf][0];
        // two col-half passes keep acc at 4x2x4 = 32 VGPRs
#pragma unroll
        for (int fch = 0; fch < 2; ++fch) {
            f32x4 acc[4][2];
#pragma unroll
            for (int fr = 0; fr < 4; ++fr)
#pragma unroll
                for (int fc = 0; fc < 2; ++fc) {
                    const float e = evc[fch * 2 + fc];
                    acc[fr][fc] = (f32x4){e, e, e, e};
                }

#pragma unroll
            for (int c = 0; c < 8; ++c) {
                const bf16x8 b0 = *(const bf16x8*)(Bc + (c * 4 + fch * 2 + 0) * 512 + l * 8);
                const bf16x8 b1 = *(const bf16x8*)(Bc + (c * 4 + fch * 2 + 1) * 512 + l * 8);
#pragma unroll
                for (int fr = 0; fr < 4; ++fr)
                    acc[fr][0] = __builtin_amdgcn_mfma_f32_16x16x32_bf16(
                        Af[fr][c], b0, acc[fr][0], 0, 0, 0);
#pragma unroll
                for (int fr = 0; fr < 4; ++fr)
                    acc[fr][1] = __builtin_amdgcn_mfma_f32_16x16x32_bf16(
                        Af[fr][c], b1, acc[fr][1], 0, 0, 0);
            }

            // fused argmin (tiles/halves/cols all ascend; strict <)
#pragma unroll
            for (int fr = 0; fr < 4; ++fr)
#pragma unroll
                for (int fc = 0; fc < 2; ++fc) {
                    const int colI = codebase + t * CT + (fch * 2 + fc) * 16 + lm;
#pragma unroll
                    for (int i = 0; i < 4; ++i) {
                        const float sc = acc[fr][fc][i];
                        const int slot = fr * 4 + i;
                        if (sc < bestV[slot]) { bestV[slot] = sc; bestI[slot] = colI; }
                    }
                }
        }
#pragma unroll
        for (int fc = 0; fc < 4; ++fc) evc[fc] = evn[fc];

        __syncthreads();   // drain covered by the sibling block on this CU
        buf ^= 1;
    }

    // cross-lane argmin over the 16 col-lanes (lane bits 0..3 = lm)
#pragma unroll
    for (int s = 0; s < 16; ++s) {
#pragma unroll
        for (int m = 1; m < 16; m <<= 1) {
            const float v2 = __shfl_xor(bestV[s], m);
            const int   i2 = __shfl_xor(bestI[s], m);
            if (v2 < bestV[s] || (v2 == bestV[s] && i2 < bestI[s])) {
                bestV[s] = v2; bestI[s] = i2;
            }
        }
    }
    // rows partition across waves: direct global writeout, no LDS reduction
    if (lm == 0) {
#pragma unroll
        for (int s = 0; s < 16; ++s) {   // row = w*64 + fr*16 + lq*4 + i
            const int rl = w * 64 + (s >> 2) * 16 + lq * 4 + (s & 3);
            const int row = rowbase + rl;
            pV[row * KG + kg] = bestV[s];
            pI[row * KG + kg] = bestI[s];
        }
    }
}

// ---- kernel C: combine K-groups, gather (fp32), STE out, loss partials ----
__global__ __launch_bounds__(256)
void vq_finalize(const float* __restrict__ z, const float* __restrict__ cb,
                 const float* __restrict__ pV, const int* __restrict__ pI,
                 float* __restrict__ out, float* __restrict__ bsum) {
    __shared__ float sSum[4];
    __shared__ int   sIdx[4];
    const int tid = threadIdx.x;
    const int rw = tid >> 6, lane = tid & 63;
    const int row = blockIdx.x * 4 + rw;

    if (lane == 0) {  // ascending kg = ascending index; strict < keeps first
        float v = pV[row * KG]; int bi = pI[row * KG];
#pragma unroll
        for (int q = 1; q < KG; ++q) {
            const float v2 = pV[row * KG + q]; const int i2 = pI[row * KG + q];
            if (v2 < v || (v2 == v && i2 < bi)) { v = v2; bi = i2; }
        }
        sIdx[rw] = bi;
    }
    __syncthreads();
    const int idx = sIdx[rw];

    const float4 zv = *(const float4*)(z  + (size_t)row * DDIM + lane * 4);
    const float4 ev = *(const float4*)(cb + (size_t)idx * DDIM + lane * 4);
    float4 d, o;
    d.x = ev.x - zv.x; d.y = ev.y - zv.y; d.z = ev.z - zv.z; d.w = ev.w - zv.w;
    o.x = zv.x + d.x;  o.y = zv.y + d.y;  o.z = zv.z + d.z;  o.w = zv.w + d.w;
    *(float4*)(out + (size_t)row * DDIM + lane * 4) = o;

    float s = d.x * d.x + d.y * d.y + d.z * d.z + d.w * d.w;
    for (int off = 32; off > 0; off >>= 1) s += __shfl_down(s, off);
    if (lane == 0) sSum[rw] = s;
    __syncthreads();
    if (tid == 0) bsum[blockIdx.x] = sSum[0] + sSum[1] + sSum[2] + sSum[3];
}

// ---- kernel D: loss ----
__global__ __launch_bounds__(256)
void loss_final(const float* __restrict__ bsum, float* __restrict__ out) {
    __shared__ float red[4];
    const int tid = threadIdx.x;
    float s = 0.f;
    for (int i = tid; i < NROWS / 4; i += 256) s += bsum[i];
    for (int off = 32; off > 0; off >>= 1) s += __shfl_down(s, off);
    const int wv = tid >> 6, lane = tid & 63;
    if (lane == 0) red[wv] = s;
    __syncthreads();
    if (tid == 0) {
        const float tot = red[0] + red[1] + red[2] + red[3];
        out[(size_t)NROWS * DDIM] = tot * (1.25f / (float)((size_t)NROWS * DDIM));
    }
}

extern "C" void kernel_launch(void* const* d_in, const int* in_sizes, int n_in,
                              void* d_out, int out_size, void* d_ws, size_t ws_size,
                              hipStream_t stream) {
    const float* z  = (const float*)d_in[0];
    const float* cb = (const float*)d_in[1];
    float* out = (float*)d_out;

    // bf16 codebook staged at head of d_out (4 MB; consumed by vq_mfma
    // before vq_finalize overwrites the region)
    __bf16* cbf = (__bf16*)d_out;

    // workspace carve (~1.1 MB)
    float* esq  = (float*)d_ws;                 // 8192
    float* pV   = esq + NCODES;                 // 32768*4
    int*   pI   = (int*)(pV + NROWS * KG);      // 32768*4
    float* bsum = (float*)(pI + NROWS * KG);    // 8192

    cvt_cb<<<NCODES * DDIM / 8 / 256, 256, 0, stream>>>(cb, cbf, esq);
    vq_mfma<<<(NROWS / RPB) * KG, 256, 0, stream>>>(z, cbf, esq, pV, pI);
    vq_finalize<<<NROWS / 4, 256, 0, stream>>>(z, cb, pV, pI, out, bsum);
    loss_final<<<1, 256, 0, stream>>>(bsum, out);
}